// Round 2
// baseline (524.083 us; speedup 1.0000x reference)
//
#include <hip/hip_runtime.h>

// TTFS encoder: out[b][t][n] = 1.0f at the first t where the leaky-integrate
// membrane crosses V_TH=1.0, else 0.0f. Membrane resets on spike but output
// only records the FIRST spike, so post-first dynamics are irrelevant to the
// output (we still iterate them cheaply; they cannot re-emit).
//
// Bit-exactness notes (output is {0,1}: one flipped element = absmax 1.0):
//  - decay = fp32(exp(-0.5)). Correctly-rounded fp32 constant; true value is
//    0.08 ulp from the representable 10175896*2^-24, so any faithful exp
//    implementation in the reference rounds to the same fp32.
//  - mem update MUST be mul-then-add with round-to-nearest, NOT fma:
//    __fmul_rn/__fadd_rn block -ffp-contract=fast.
//  - (1.0f - decay) is exact in fp32, so c*(1-decay) matches the reference.

#define T_STEPS 64
#define N_COLS  1024

// Native clang vector type: __builtin_nontemporal_store requires a real
// vector type, not HIP's class-based float4.
typedef float vfloat4 __attribute__((ext_vector_type(4)));

__global__ __launch_bounds__(256) void ttfs_encode_kernel(
    const float* __restrict__ x,
    const float* __restrict__ sens,
    float* __restrict__ out)
{
    const int b   = blockIdx.x;
    const int tid = threadIdx.x;      // 0..255, each owns 4 consecutive cols
    const int n0  = tid * 4;

    const float decay = 0.60653065971263342f;  // fp32(exp(-0.5)), CR
    const float omd   = 1.0f - decay;          // exact (Sterbenz)

    const vfloat4 xv = *reinterpret_cast<const vfloat4*>(x + (size_t)b * N_COLS + n0);
    const vfloat4 sv = *reinterpret_cast<const vfloat4*>(sens + n0);

    // b_i = (x*s)*(1-decay): two rn muls, matching reference op order.
    float drive[4];
    #pragma unroll
    for (int i = 0; i < 4; ++i)
        drive[i] = __fmul_rn(__fmul_rn(xv[i], sv[i]), omd);

    float mem[4]   = {0.f, 0.f, 0.f, 0.f};
    bool  fired[4] = {false, false, false, false};

    float* outp = out + (size_t)b * T_STEPS * N_COLS + n0;

    #pragma unroll 4
    for (int t = 0; t < T_STEPS; ++t) {
        vfloat4 ov;
        #pragma unroll
        for (int i = 0; i < 4; ++i) {
            float m = __fadd_rn(__fmul_rn(mem[i], decay), drive[i]);
            const bool spike = (m >= 1.0f);
            ov[i] = (spike && !fired[i]) ? 1.0f : 0.0f;
            fired[i] = fired[i] || spike;
            mem[i] = spike ? 0.0f : m;
        }
        // Streaming write-once output: nontemporal, skip L2 residency.
        __builtin_nontemporal_store(ov, reinterpret_cast<vfloat4*>(outp));
        outp += N_COLS;
    }
}

extern "C" void kernel_launch(void* const* d_in, const int* in_sizes, int n_in,
                              void* d_out, int out_size, void* d_ws, size_t ws_size,
                              hipStream_t stream) {
    const float* x    = (const float*)d_in[0];   // [B, N] fp32
    const float* sens = (const float*)d_in[1];   // [N]    fp32
    float*       out  = (float*)d_out;           // [B, T, N] fp32

    const int N = in_sizes[1];                   // 1024
    const int B = in_sizes[0] / N;               // 2048
    (void)N; (void)out_size; (void)d_ws; (void)ws_size; (void)n_in;

    ttfs_encode_kernel<<<dim3(B), dim3(256), 0, stream>>>(x, sens, out);
}

// Round 3
// 522.214 us; speedup vs baseline: 1.0036x; 1.0036x over previous
//
#include <hip/hip_runtime.h>

// TTFS encoder: out[b][t][n] = 1.0f at the first t where the leaky-integrate
// membrane crosses V_TH=1.0, else 0.0f. Membrane resets on spike but output
// only records the FIRST spike.
//
// Bit-exactness notes (output is {0,1}: one flipped element = absmax 1.0):
//  - decay = fp32(exp(-0.5)). Correctly-rounded fp32 constant; true value is
//    0.08 ulp from the representable grid point, so any faithful exp in the
//    reference rounds to the same fp32.
//  - mem update MUST be mul-then-add with round-to-nearest, NOT fma:
//    __fmul_rn/__fadd_rn block -ffp-contract=fast.
//  - (1.0f - decay) is exact in fp32 (Sterbenz), so c*(1-decay) matches.
//
// R2 post-mortem: nontemporal stores left us ≥2x off the write roofline while
// the harness's own fillBufferAligned (plain stores) hit 6.24 TB/s on the same
// buffer. Theory: nt bypasses L2 write-combining -> sub-line HBM writes.
// This round: plain float4 stores (single-variable A/B vs R2).

#define T_STEPS 64
#define N_COLS  1024

typedef float vfloat4 __attribute__((ext_vector_type(4)));

__global__ __launch_bounds__(256) void ttfs_encode_kernel(
    const float* __restrict__ x,
    const float* __restrict__ sens,
    float* __restrict__ out)
{
    const int b   = blockIdx.x;
    const int tid = threadIdx.x;      // 0..255, each owns 4 consecutive cols
    const int n0  = tid * 4;

    const float decay = 0.60653065971263342f;  // fp32(exp(-0.5)), CR
    const float omd   = 1.0f - decay;          // exact (Sterbenz)

    const vfloat4 xv = *reinterpret_cast<const vfloat4*>(x + (size_t)b * N_COLS + n0);
    const vfloat4 sv = *reinterpret_cast<const vfloat4*>(sens + n0);

    // drive_i = (x*s)*(1-decay): two rn muls, matching reference op order.
    float drive[4];
    #pragma unroll
    for (int i = 0; i < 4; ++i)
        drive[i] = __fmul_rn(__fmul_rn(xv[i], sv[i]), omd);

    float mem[4]   = {0.f, 0.f, 0.f, 0.f};
    bool  fired[4] = {false, false, false, false};

    float* outp = out + (size_t)b * T_STEPS * N_COLS + n0;

    #pragma unroll 4
    for (int t = 0; t < T_STEPS; ++t) {
        vfloat4 ov;
        #pragma unroll
        for (int i = 0; i < 4; ++i) {
            float m = __fadd_rn(__fmul_rn(mem[i], decay), drive[i]);
            const bool spike = (m >= 1.0f);
            ov[i] = (spike && !fired[i]) ? 1.0f : 0.0f;
            fired[i] = fired[i] || spike;
            mem[i] = spike ? 0.0f : m;
        }
        // Plain (L2 write-back) store: lets L2 combine into full HBM bursts.
        *reinterpret_cast<vfloat4*>(outp) = ov;
        outp += N_COLS;
    }
}

extern "C" void kernel_launch(void* const* d_in, const int* in_sizes, int n_in,
                              void* d_out, int out_size, void* d_ws, size_t ws_size,
                              hipStream_t stream) {
    const float* x    = (const float*)d_in[0];   // [B, N] fp32
    const float* sens = (const float*)d_in[1];   // [N]    fp32
    float*       out  = (float*)d_out;           // [B, T, N] fp32

    const int N = in_sizes[1];                   // 1024
    const int B = in_sizes[0] / N;               // 2048
    (void)N; (void)out_size; (void)d_ws; (void)ws_size; (void)n_in;

    ttfs_encode_kernel<<<dim3(B), dim3(256), 0, stream>>>(x, sens, out);
}